// Round 2
// baseline (166.840 us; speedup 1.0000x reference)
//
#include <hip/hip_runtime.h>
#include <hip/hip_bf16.h>
#include <stdint.h>
#include <stddef.h>

// Problem constants (from reference)
#define NUM_FEATURES 256
#define NUM_PIDS 5532
#define CQ_SIZE 5000
#define N_NONID 256
#define N_ROWS 2048
#define N_COLS (NUM_PIDS + CQ_SIZE + N_NONID)   // 10788
#define OIM_SCALAR 30.0f

// Tile config: 128x128 tile, BK=32, 4 waves (2x2) each computing 64x64
#define BM 128
#define BN 128
#define BK 32
#define KITERS (NUM_FEATURES / BK)   // 8

typedef __bf16 bf16_t;
typedef __bf16 bf16x4 __attribute__((ext_vector_type(4)));
typedef __bf16 bf16x8 __attribute__((ext_vector_type(8)));   // MFMA A/B frag (4 VGPRs)
typedef float f32x4 __attribute__((ext_vector_type(4)));     // MFMA C/D frag

// ---------------------------------------------------------------------------
// dtype detector: reference rows are unit-norm. Interpret first 512 B of
// `inputs` as 256 bf16. If true dtype is bf16 -> exactly row 0 -> sumsq ~ 1.
// If true dtype is fp32 -> half those words are fp32 low-mantissa bits with
// random exponent fields -> sumsq blows up (inf) with overwhelming prob.
// flag = 1 -> bf16 mode, 0 -> fp32 mode.
// ---------------------------------------------------------------------------
__global__ void detect_dtype(const void* __restrict__ A, int* __restrict__ flag) {
    const bf16_t* ab = (const bf16_t*)A;
    const int lane = threadIdx.x;   // 64 threads
    float s = 0.0f;
    #pragma unroll
    for (int j = 0; j < 4; ++j) {
        float x = (float)ab[lane * 4 + j];
        s += x * x;
    }
    #pragma unroll
    for (int off = 32; off > 0; off >>= 1) s += __shfl_down(s, off, 64);
    if (lane == 0) flag[0] = (s > 0.75f && s < 1.25f) ? 1 : 0;
}

// ---------------------------------------------------------------------------
// GEMM body, templated on input/output element type (F32 true -> fp32 I/O,
// converting to bf16 for MFMA; F32 false -> native bf16 I/O).
// ---------------------------------------------------------------------------
template <bool F32>
__device__ __forceinline__ void gemm_body(
    const char* __restrict__ A, const char* __restrict__ lut,
    const char* __restrict__ cq, const char* __restrict__ nonid,
    char* __restrict__ out, bf16_t* As, bf16_t* Bs)
{
    constexpr int ES = F32 ? 4 : 2;          // element size in bytes
    const int tid  = threadIdx.x;
    const int wid  = tid >> 6;
    const int lane = tid & 63;
    const int m0 = blockIdx.y * BM;
    const int n0 = blockIdx.x * BN;

    // --- staging coords: each thread moves 16 elements of A and B per k-iter
    // F32 : j=0..3, row=(tid>>3)+j*32, kk=(tid&7)*4  (one float4 each)
    // BF16: j=0..1, row=(tid>>2)+j*64, kk=(tid&3)*8  (one bf16x8 each)
    constexpr int NJ    = F32 ? 4 : 2;
    constexpr int RSTEP = F32 ? 32 : 64;
    const int srow = F32 ? (tid >> 3) : (tid >> 2);
    const int skk  = F32 ? ((tid & 7) * 4) : ((tid & 3) * 8);

    const char* arow[NJ];
    const char* brow[NJ];
    #pragma unroll
    for (int j = 0; j < NJ; ++j) {
        const int rm = m0 + srow + j * RSTEP;
        arow[j] = A + ((size_t)rm * NUM_FEATURES + skk) * ES;
        int r = n0 + srow + j * RSTEP;
        r = r < (N_COLS - 1) ? r : (N_COLS - 1);   // clamp tail tile (stores guarded)
        const char* src;
        if (r < NUM_PIDS)                 src = lut   + (size_t)r * NUM_FEATURES * ES;
        else if (r < NUM_PIDS + CQ_SIZE)  src = cq    + (size_t)(r - NUM_PIDS) * NUM_FEATURES * ES;
        else                              src = nonid + (size_t)(r - NUM_PIDS - CQ_SIZE) * NUM_FEATURES * ES;
        brow[j] = src + (size_t)skk * ES;
    }

    // --- MFMA fragment coords (verified layouts, learn_hip m89/m91/m120) ---
    const int wave_m = (wid >> 1) * 64;
    const int wave_n = (wid & 1) * 64;
    const int fr = lane & 15;             // A/B frag: m (or n) = lane&15
    const int fk = (lane >> 4) * 8;       // k = (lane>>4)*8 + j, 8 contiguous

    f32x4 acc[4][4] = {};

    for (int kt = 0; kt < KITERS; ++kt) {
        #pragma unroll
        for (int j = 0; j < NJ; ++j) {
            const int ldix = (srow + j * RSTEP) * BK + skk;
            if constexpr (F32) {
                float4 av = *(const float4*)arow[j];
                float4 bv = *(const float4*)brow[j];
                bf16x4 ac = { (bf16_t)av.x, (bf16_t)av.y, (bf16_t)av.z, (bf16_t)av.w };
                bf16x4 bc = { (bf16_t)bv.x, (bf16_t)bv.y, (bf16_t)bv.z, (bf16_t)bv.w };
                *(bf16x4*)&As[ldix] = ac;
                *(bf16x4*)&Bs[ldix] = bc;
            } else {
                *(bf16x8*)&As[ldix] = *(const bf16x8*)arow[j];
                *(bf16x8*)&Bs[ldix] = *(const bf16x8*)brow[j];
            }
            arow[j] += BK * ES;
            brow[j] += BK * ES;
        }
        __syncthreads();

        bf16x8 af[4], bfr[4];
        #pragma unroll
        for (int t = 0; t < 4; ++t) {
            af[t]  = *(const bf16x8*)&As[(wave_m + t * 16 + fr) * BK + fk];
            bfr[t] = *(const bf16x8*)&Bs[(wave_n + t * 16 + fr) * BK + fk];
        }
        #pragma unroll
        for (int tm = 0; tm < 4; ++tm)
            #pragma unroll
            for (int tn = 0; tn < 4; ++tn)
                acc[tm][tn] = __builtin_amdgcn_mfma_f32_16x16x32_bf16(
                    af[tm], bfr[tn], acc[tm][tn], 0, 0, 0);
        __syncthreads();
    }

    // --- epilogue: C/D layout col=lane&15, row=(lane>>4)*4+reg (m89/m91) ---
    #pragma unroll
    for (int tm = 0; tm < 4; ++tm) {
        const int row_base = m0 + wave_m + tm * 16 + (lane >> 4) * 4;
        #pragma unroll
        for (int tn = 0; tn < 4; ++tn) {
            const int col = n0 + wave_n + tn * 16 + (lane & 15);
            if (col < N_COLS) {
                #pragma unroll
                for (int i = 0; i < 4; ++i) {
                    float v = acc[tm][tn][i] * OIM_SCALAR;
                    if constexpr (F32)
                        ((float*)out)[(size_t)(row_base + i) * N_COLS + col] = v;
                    else
                        ((bf16_t*)out)[(size_t)(row_base + i) * N_COLS + col] = (bf16_t)v;
                }
            }
        }
    }
}

__global__ __launch_bounds__(256)
void oim_gemm_kernel(const void* __restrict__ A, const void* __restrict__ lut,
                     const void* __restrict__ cq, const void* __restrict__ nonid,
                     void* __restrict__ out, const int* __restrict__ flag) {
    __shared__ __align__(16) bf16_t As[BM * BK];
    __shared__ __align__(16) bf16_t Bs[BN * BK];
    if (flag[0]) {   // wave-uniform branch
        gemm_body<false>((const char*)A, (const char*)lut, (const char*)cq,
                         (const char*)nonid, (char*)out, As, Bs);
    } else {
        gemm_body<true>((const char*)A, (const char*)lut, (const char*)cq,
                        (const char*)nonid, (char*)out, As, Bs);
    }
}

extern "C" void kernel_launch(void* const* d_in, const int* in_sizes, int n_in,
                              void* d_out, int out_size, void* d_ws, size_t ws_size,
                              hipStream_t stream) {
    // setup_inputs() order:
    // 0: inputs [2048,256], 1: non_id_feat [256,256], 2: lut [5532,256],
    // 3: cq [5000,256], 4: first_pos_sample, 5: second_pos_sample,
    // 6: targets (int), 7: belong_to_first_half, 8: header
    const void* inputs = d_in[0];
    const void* nonid  = d_in[1];
    const void* lut    = d_in[2];
    const void* cq     = d_in[3];
    int* flag = (int*)d_ws;

    detect_dtype<<<1, 64, 0, stream>>>(inputs, flag);

    dim3 grid((N_COLS + BN - 1) / BN, N_ROWS / BM);  // (85, 16) = 1360 blocks
    oim_gemm_kernel<<<grid, 256, 0, stream>>>(inputs, lut, cq, nonid, d_out, flag);
}

// Round 3
// 147.486 us; speedup vs baseline: 1.1312x; 1.1312x over previous
//
#include <hip/hip_runtime.h>
#include <hip/hip_bf16.h>
#include <stdint.h>
#include <stddef.h>

// Problem constants (from reference). Harness dtype: fp32 in / fp32 out
// (verified round 2: WRITE_SIZE ~90 MB = 2048*10788*4B; F32 branch passed).
#define NUM_FEATURES 256
#define NUM_PIDS 5532
#define CQ_SIZE 5000
#define N_NONID 256
#define N_ROWS 2048
#define N_COLS (NUM_PIDS + CQ_SIZE + N_NONID)   // 10788
#define OIM_SCALAR 30.0f

// Tile config: 128x128 tile, BK=32, 4 waves (2x2) each computing 64x64.
#define BM 128
#define BN 128
#define BK 32
#define KITERS (NUM_FEATURES / BK)   // 8

// XCD swizzle: 85 n-tiles padded to 88 = 8 XCDs * 11 tiles. Grid 1408 = 8*176;
// id%8 -> XCD (round-robin dispatch heuristic); each XCD works one contiguous
// 11-tile n-slab: B-slab 1.4 MB + full A 2 MB = 3.4 MB < 4 MB per-XCD L2.
#define NT_PER_XCD 11
#define N_TILES 85
#define M_TILES 16
#define GRID_BLOCKS (8 * NT_PER_XCD * M_TILES)   // 1408 (48 dummy blocks early-exit)

typedef __bf16 bf16_t;
typedef __bf16 bf16x4 __attribute__((ext_vector_type(4)));
typedef __bf16 bf16x8 __attribute__((ext_vector_type(8)));   // MFMA A/B frag
typedef float f32x4 __attribute__((ext_vector_type(4)));     // MFMA C/D frag

__global__ __launch_bounds__(256)
void oim_gemm_kernel(const float* __restrict__ A,      // [2048][256]
                     const float* __restrict__ lut,    // [5532][256]
                     const float* __restrict__ cq,     // [5000][256]
                     const float* __restrict__ nonid,  // [256][256]
                     float* __restrict__ out) {        // [2048][10788]
    // Double-buffered LDS: 2 * (8 KB + 8 KB) = 32 KB
    __shared__ __align__(16) bf16_t As[2][BM * BK];
    __shared__ __align__(16) bf16_t Bs[2][BM * BK];

    // --- XCD-slab block swizzle ---
    const int id  = blockIdx.x;
    const int xcd = id & 7;
    const int l   = id >> 3;                  // 0..175
    const int nt  = xcd * NT_PER_XCD + l % NT_PER_XCD;
    const int mt  = l / NT_PER_XCD;           // 0..15
    if (nt >= N_TILES) return;                // dummy block (uniform, pre-barrier)
    const int m0 = mt * BM;
    const int n0 = nt * BN;

    const int tid  = threadIdx.x;
    const int wid  = tid >> 6;
    const int lane = tid & 63;

    // --- staging coords: each thread loads 4x float4 of A and of B per k-tile
    // j=0..3: row = srow + j*32, k = skk..skk+3
    const int srow = tid >> 3;                // 0..31
    const int skk  = (tid & 7) * 4;           // 0,4,..,28

    const float* arow[4];
    const float* brow[4];
    #pragma unroll
    for (int j = 0; j < 4; ++j) {
        const int rm = m0 + srow + j * 32;
        arow[j] = A + (size_t)rm * NUM_FEATURES + skk;
        int r = n0 + srow + j * 32;
        r = r < (N_COLS - 1) ? r : (N_COLS - 1);   // clamp tail (stores guarded)
        const float* src;
        if (r < NUM_PIDS)                 src = lut   + (size_t)r * NUM_FEATURES;
        else if (r < NUM_PIDS + CQ_SIZE)  src = cq    + (size_t)(r - NUM_PIDS) * NUM_FEATURES;
        else                              src = nonid + (size_t)(r - NUM_PIDS - CQ_SIZE) * NUM_FEATURES;
        brow[j] = src + skk;
    }

    // --- MFMA fragment coords (verified m89/m91) ---
    const int wave_m = (wid >> 1) * 64;
    const int wave_n = (wid & 1) * 64;
    const int fr = lane & 15;                 // A/B frag: m (or n) = lane&15
    const int fk = (lane >> 4) * 8;           // k = (lane>>4)*8 + j

    f32x4 acc[4][4] = {};

    // --- prologue: prefetch k-tile 0 into registers ---
    float4 areg[4], breg[4];
    #pragma unroll
    for (int j = 0; j < 4; ++j) {
        areg[j] = *(const float4*)arow[j];
        breg[j] = *(const float4*)brow[j];
        arow[j] += BK;
        brow[j] += BK;
    }

    // --- single-barrier double-buffered K-loop ---
    // Structure: cvt+write LDS(buf) -> barrier -> issue next global loads ->
    // ds_read frags + MFMA. In-flight loads are consumed at the next
    // iteration's LDS write (before its barrier), so the barrier's vmcnt(0)
    // drain never waits on a prefetch (m97 stall avoided).
    #pragma unroll 2
    for (int kt = 0; kt < KITERS; ++kt) {
        bf16_t* const as = As[kt & 1];
        bf16_t* const bs = Bs[kt & 1];
        #pragma unroll
        for (int j = 0; j < 4; ++j) {
            const int ldix = (srow + j * 32) * BK + skk;
            bf16x4 ac = { (bf16_t)areg[j].x, (bf16_t)areg[j].y,
                          (bf16_t)areg[j].z, (bf16_t)areg[j].w };
            bf16x4 bc = { (bf16_t)breg[j].x, (bf16_t)breg[j].y,
                          (bf16_t)breg[j].z, (bf16_t)breg[j].w };
            *(bf16x4*)&as[ldix] = ac;
            *(bf16x4*)&bs[ldix] = bc;
        }
        __syncthreads();
        if (kt < KITERS - 1) {
            #pragma unroll
            for (int j = 0; j < 4; ++j) {
                areg[j] = *(const float4*)arow[j];
                breg[j] = *(const float4*)brow[j];
                arow[j] += BK;
                brow[j] += BK;
            }
        }
        bf16x8 af[4], bfr[4];
        #pragma unroll
        for (int t = 0; t < 4; ++t) {
            af[t]  = *(const bf16x8*)&as[(wave_m + t * 16 + fr) * BK + fk];
            bfr[t] = *(const bf16x8*)&bs[(wave_n + t * 16 + fr) * BK + fk];
        }
        #pragma unroll
        for (int tm = 0; tm < 4; ++tm)
            #pragma unroll
            for (int tn = 0; tn < 4; ++tn)
                acc[tm][tn] = __builtin_amdgcn_mfma_f32_16x16x32_bf16(
                    af[tm], bfr[tn], acc[tm][tn], 0, 0, 0);
        // no second barrier: double-buffer parity + next iteration's barrier
        // order writes of tile kt+2 after all reads of tile kt.
    }

    // --- epilogue: scale by 30, fp32 store ---
    // C/D layout (verified m89/m91): col = lane&15, row = (lane>>4)*4 + reg
    #pragma unroll
    for (int tm = 0; tm < 4; ++tm) {
        const int row_base = m0 + wave_m + tm * 16 + (lane >> 4) * 4;
        #pragma unroll
        for (int tn = 0; tn < 4; ++tn) {
            const int col = n0 + wave_n + tn * 16 + (lane & 15);
            if (col < N_COLS) {
                #pragma unroll
                for (int i = 0; i < 4; ++i) {
                    out[(size_t)(row_base + i) * N_COLS + col] =
                        acc[tm][tn][i] * OIM_SCALAR;
                }
            }
        }
    }
}

extern "C" void kernel_launch(void* const* d_in, const int* in_sizes, int n_in,
                              void* d_out, int out_size, void* d_ws, size_t ws_size,
                              hipStream_t stream) {
    // setup_inputs() order:
    // 0: inputs [2048,256], 1: non_id_feat [256,256], 2: lut [5532,256],
    // 3: cq [5000,256], 4: first_pos_sample, 5: second_pos_sample,
    // 6: targets (int), 7: belong_to_first_half, 8: header
    const float* inputs = (const float*)d_in[0];
    const float* nonid  = (const float*)d_in[1];
    const float* lut    = (const float*)d_in[2];
    const float* cq     = (const float*)d_in[3];
    float* out = (float*)d_out;

    oim_gemm_kernel<<<dim3(GRID_BLOCKS), 256, 0, stream>>>(inputs, lut, cq, nonid, out);
}